// Round 15
// baseline (83.735 us; speedup 1.0000x reference)
//
#include <hip/hip_runtime.h>

#define BATCH 4
#define NPTS  4096
#define TPB   512                       // 8 waves per block
#define PC    64                        // P points per block
#define NPG   16                        // P groups per block (t & 15)
#define PPT   4                         // P points per thread
#define NZZ   32                        // Q slices per block (t >> 4)
#define QSL   (NPTS / NZZ)              // 128 Q per slice
#define NBLK  (2 * BATCH * (NPTS / PC)) // 512 blocks

// m = min(m, a, b) in one instruction (non-volatile: schedulable, CSE-safe).
__device__ __forceinline__ void min3(float& m, float a, float b) {
    asm("v_min3_f32 %0, %0, %1, %2" : "+v"(m) : "v"(a), "v"(b));
}
// |a| + |b| via guaranteed VOP3 abs input modifiers (1 instruction each).
__device__ __forceinline__ float add_abs2(float a, float b) {
    float d;
    asm("v_add_f32 %0, |%1|, |%2|" : "=v"(d) : "v"(a), "v"(b));
    return d;
}
__device__ __forceinline__ float add_abs1(float acc, float c) {
    float d;
    asm("v_add_f32 %0, %1, |%2|" : "=v"(d) : "v"(acc), "v"(c));
    return d;
}

// L1 distances for 4 P (regs) x 4 consecutive Q (three float4 loads).
__device__ __forceinline__ void dist4x4(const float4 g0, const float4 g1,
                                        const float4 g2, const float px[PPT],
                                        const float py[PPT], const float pz[PPT],
                                        float m[PPT]) {
    #pragma unroll
    for (int u = 0; u < PPT; ++u) {
        float dA = add_abs1(add_abs2(px[u] - g0.x, py[u] - g0.y), pz[u] - g0.z);
        float dB = add_abs1(add_abs2(px[u] - g0.w, py[u] - g1.x), pz[u] - g1.y);
        float dC = add_abs1(add_abs2(px[u] - g1.z, py[u] - g1.w), pz[u] - g2.x);
        float dD = add_abs1(add_abs2(px[u] - g2.y, py[u] - g2.z), pz[u] - g2.w);
        min3(m[u], dA, dB);
        min3(m[u], dC, dD);
    }
}

// SINGLE fused kernel. Block = (dir, b, 64-point P chunk); the block's 512
// threads partition Q into 32 slices of 128 (zz = t>>4), so each block
// produces FINAL mins for its 64 P points -> in-block combine (LDS atomicMin
// on uint bits; distances >= 0 so float order == uint order) -> block sum ->
// last-block finalize via counter (pre-zeroed by hipMemsetAsync).
// Cross-XCD handoff: psum release-store + ACQ_REL agent-scope fetch_add on
// cnt (release sequence -> last block's RMW acquires every block's psum;
// per-XCD L2s are not coherent, so plain ld/st would risk stale lines).
// Per distance: 3 v_sub + 2 v_add(|.|) + 0.5 v_min3 = 5.5 VALU lane-ops.
__global__ __launch_bounds__(TPB) void chamfer_fused(const float* __restrict__ X,
                                                     const float* __restrict__ Y,
                                                     unsigned int* __restrict__ cnt,
                                                     float* __restrict__ psum,
                                                     float* __restrict__ out) {
    const int t   = threadIdx.x;
    const int pg  = t & (NPG - 1);
    const int zz  = t >> 4;
    const int bid = blockIdx.x;
    const int x   = bid & 63;           // P chunk index (4096/64)
    const int db  = bid >> 6;           // 0..7
    const int b   = db & 3;
    const float* __restrict__ P = (db >> 2) ? Y : X;
    const float* __restrict__ Q = (db >> 2) ? X : Y;

    // 4 consecutive P points: 3 x dwordx4 (48 B, 16B-aligned since index %4==0)
    const float4* __restrict__ Ps =
        (const float4*)(P + ((size_t)b * NPTS + x * PC + pg * PPT) * 3);
    const float4 f0 = Ps[0], f1 = Ps[1], f2 = Ps[2];
    float px[PPT], py[PPT], pz[PPT], m[PPT];
    px[0]=f0.x; py[0]=f0.y; pz[0]=f0.z;  px[1]=f0.w; py[1]=f1.x; pz[1]=f1.y;
    px[2]=f1.z; py[2]=f1.w; pz[2]=f2.x;  px[3]=f2.y; py[3]=f2.z; pz[3]=f2.w;
    #pragma unroll
    for (int u = 0; u < PPT; ++u) m[u] = __builtin_inff();

    // Scan this thread's 128-Q slice straight from global (L1/L2 resident;
    // 16 lanes share each address -> broadcast fetch; 3 loads / 88 VALU).
    const float4* __restrict__ Qs =
        (const float4*)(Q + ((size_t)b * NPTS + zz * QSL) * 3);
    #pragma unroll 4
    for (int j = 0; j < (QSL / 4) * 3; j += 3) {
        const float4 g0 = Qs[j], g1 = Qs[j + 1], g2 = Qs[j + 2];
        dist4x4(g0, g1, g2, px, py, pz, m);
    }

    // ---- in-block combine: 64 final mins, then one block sum ----
    __shared__ unsigned int smin[PC];
    __shared__ int lastf;
    if (t < PC) smin[t] = 0x7F800000u;  // +inf
    __syncthreads();
    #pragma unroll
    for (int u = 0; u < PPT; ++u)
        atomicMin(&smin[pg * PPT + u], __float_as_uint(m[u]));
    __syncthreads();

    if (t < 64) {
        float v = __uint_as_float(smin[t]);
        #pragma unroll
        for (int off = 32; off > 0; off >>= 1) v += __shfl_down(v, off, 64);
        if (t == 0) {
            __hip_atomic_store(&psum[bid], v, __ATOMIC_RELEASE,
                               __HIP_MEMORY_SCOPE_AGENT);
            unsigned int old = __hip_atomic_fetch_add(
                cnt, 1u, __ATOMIC_ACQ_REL, __HIP_MEMORY_SCOPE_AGENT);
            lastf = (old == NBLK - 1);
        }
    }
    __syncthreads();

    // ---- last block sums the 512 per-block partials and writes the loss ----
    if (lastf) {
        float s = __hip_atomic_load(&psum[t], __ATOMIC_ACQUIRE,
                                    __HIP_MEMORY_SCOPE_AGENT);   // NBLK == TPB
        #pragma unroll
        for (int off = 32; off > 0; off >>= 1) s += __shfl_down(s, off, 64);
        __shared__ float wsum[TPB / 64];
        if ((t & 63) == 0) wsum[t >> 6] = s;
        __syncthreads();
        if (t == 0) {
            float tot = 0.f;
            #pragma unroll
            for (int w = 0; w < TPB / 64; ++w) tot += wsum[w];
            // mean(cham_x) + mean(cham_y) = (sum_x + sum_y) / (B*N), N == M
            out[0] = tot * (1.0f / (float)(BATCH * NPTS));
        }
    }
}

extern "C" void kernel_launch(void* const* d_in, const int* in_sizes, int n_in,
                              void* d_out, int out_size, void* d_ws, size_t ws_size,
                              hipStream_t stream) {
    const float* X = (const float*)d_in[0];
    const float* Y = (const float*)d_in[1];
    float* out = (float*)d_out;

    unsigned int* cnt = (unsigned int*)d_ws;        // 4 B counter
    float* psum = (float*)d_ws + 16;                // 512 partials (64B offset)

    hipMemsetAsync(cnt, 0, sizeof(unsigned int), stream);  // capturable
    chamfer_fused<<<NBLK, TPB, 0, stream>>>(X, Y, cnt, psum, out);
}